// Round 6
// baseline (112.388 us; speedup 1.0000x reference)
//
#include <hip/hip_runtime.h>
#include <cstddef>
#include <cstdint>

// EdgeSheafLaplacian: n=1024 nodes, stalk d=8, P=32768 directed edges.
// Output Delta (8192 x 8192) f32: only 1024 diag + P edge blocks nonzero.
//
// R6: bucket edges (O(P)); wave-specialized writer kernel.
//   memset cnt (4 KiB)
//   K1 k_count:   rowlist[i] <- p for each directed edge p=(i,j)
//   K2 k_diagdis: 1024 blocks, 4 waves/node: FtF partials over bucket list,
//                 LDS-reduce, Newton-Schulz D^{-1/2} on wave 0.
//                 (valid: D = sum-of-Wisharts + eps I => lambda_min >> eps,
//                  reference's clip(w,EPS) inactive; eigh not needed)
//   K3 k_out:     per block-row i: waves 0-2 stream 256 KiB of zeros (pure
//                 stores, no loads -> fill-rate); wave 3 concurrently computes
//                 diag + edge blocks (Dis_i*M*Dis_j) into LDS; barrier (drains
//                 stores); all waves scatter blocks from LDS over the zeros.
// Reverse edge is structural: directed = [lo,hi ; hi,lo] concat -> rev = p +- P/2
// (verified in-kernel; mismatch or sign(L1)==0 -> block is exactly zero).

namespace {
constexpr int N = 1024;
constexpr int ND = 8192;
constexpr int MAXB = 96;  // bucket capacity (deg mean 32, sigma ~5.7)
}

__global__ __launch_bounds__(256) void k_count(const int* __restrict__ eidx, int P,
                                               int* __restrict__ cnt,
                                               int* __restrict__ rowlist) {
  int p = blockIdx.x * blockDim.x + threadIdx.x;
  if (p >= P) return;
  int i = ((const int2*)eidx)[p].x;
  int slot = atomicAdd(&cnt[i], 1);
  if (slot < MAXB) rowlist[i * MAXB + slot] = p;
}

__global__ __launch_bounds__(256) void k_diagdis(const float* __restrict__ R,
                                                 const int* __restrict__ cnt,
                                                 const int* __restrict__ rowlist,
                                                 float* __restrict__ diag,
                                                 float* __restrict__ Dis) {
  const int v = blockIdx.x;
  const int tid = threadIdx.x;
  const int wid = tid >> 6, lane = tid & 63;
  const int a = lane >> 3, b = lane & 7;
  int c = cnt[v];
  if (c > MAXB) c = MAXB;
  float acc = 0.f;
  for (int s = wid; s < c; s += 4) {
    int p = rowlist[v * MAXB + s];
    float r = R[(size_t)p * 64 + lane];
#pragma unroll
    for (int k = 0; k < 8; ++k)
      acc += __shfl(r, k * 8 + a, 64) * __shfl(r, k * 8 + b, 64);
  }
  __shared__ float part[4][64];
  part[wid][lane] = acc;
  __syncthreads();
  if (wid != 0) return;
  float tot = (part[0][lane] + part[1][lane]) + (part[2][lane] + part[3][lane]);
  diag[v * 64 + lane] = tot;  // bitwise symmetric (commutative products, fixed order)
  float A = tot + (a == b ? 1e-4f : 0.f);
  float sq = A * A;
#pragma unroll
  for (int off = 32; off; off >>= 1) sq += __shfl_xor(sq, off, 64);
  float fro = sqrtf(sq);
  // Newton-Schulz: Y0 = A/fro (spectrum in (0,1]), Z0 = I; Z -> (A/fro)^{-1/2}
  float Y = A * (1.f / fro);
  float Z = (a == b) ? 1.f : 0.f;
  for (int it = 0; it < 14; ++it) {
    float T = 0.f;
#pragma unroll
    for (int k = 0; k < 8; ++k)
      T += __shfl(Z, a * 8 + k, 64) * __shfl(Y, k * 8 + b, 64);
    float G = ((a == b) ? 1.5f : 0.f) - 0.5f * T;  // (3I - ZY)/2
    float Yn = 0.f, Zn = 0.f;
#pragma unroll
    for (int k = 0; k < 8; ++k) {
      Yn += __shfl(Y, a * 8 + k, 64) * __shfl(G, k * 8 + b, 64);
      Zn += __shfl(G, a * 8 + k, 64) * __shfl(Z, k * 8 + b, 64);
    }
    Y = Yn;
    Z = Zn;
  }
  Dis[v * 64 + lane] = Z * (1.f / sqrtf(fro));
}

__global__ __launch_bounds__(256) void k_out(
    const float* __restrict__ R, const int* __restrict__ eidx,
    const float* __restrict__ L1, const int* __restrict__ cnt,
    const int* __restrict__ rowlist, const float* __restrict__ diag,
    const float* __restrict__ Dis, int P, float* __restrict__ out) {
  const int i = blockIdx.x;
  const int tid = threadIdx.x;
  const int wid = tid >> 6, lane = tid & 63;
  const int a = lane >> 3, b = lane & 7;
  __shared__ float Bc[MAXB + 1][64];
  __shared__ int jl[MAXB + 1];

  int c = cnt[i];
  if (c > MAXB) c = MAXB;

  if (wid < 3) {
    // ---- pure zero-stream of rows [8i, 8i+8): 16384 float4 = 256 KiB ----
    // No loads, no branches in the loop body: issues at fill rate.
    float4 z = {0.f, 0.f, 0.f, 0.f};
    float4* ob = (float4*)(out + (size_t)i * 8 * ND);
    for (int t = wid * 64 + lane; t < 16384; t += 192)
      ob[t] = z;
  } else {
    // ---- wave 3: compute diag + edge blocks into LDS (overlaps the stream) ----
    const float di = Dis[i * 64 + lane];
    {
      float M = diag[i * 64 + lane];
      float T = 0.f;
#pragma unroll
      for (int k = 0; k < 8; ++k)
        T += __shfl(M, a * 8 + k, 64) * __shfl(di, k * 8 + b, 64);
      float o = 0.f;
#pragma unroll
      for (int k = 0; k < 8; ++k)
        o += __shfl(di, a * 8 + k, 64) * __shfl(T, k * 8 + b, 64);
      Bc[0][lane] = o;
      if (lane == 0) jl[0] = i;
    }
    const int halfP = P >> 1;
    for (int s = 0; s < c; ++s) {
      int p = rowlist[i * MAXB + s];
      int jb = eidx[2 * p + 1];
      int rev = (p < halfP) ? p + halfP : p - halfP;  // structural reverse edge
      bool ok = (eidx[2 * rev] == jb) && (eidx[2 * rev + 1] == i);
      float l1v = L1[i * N + jb];
      float sgn = (l1v > 0.f ? 1.f : 0.f) - (l1v < 0.f ? 1.f : 0.f);
      float rp = R[(size_t)p * 64 + lane];
      float rr = R[(size_t)rev * 64 + lane];
      float m = 0.f;
#pragma unroll
      for (int k = 0; k < 8; ++k)
        m += __shfl(rr, k * 8 + a, 64) * __shfl(rp, k * 8 + b, 64);
      float M = ok ? (-sgn * m) : 0.f;
      float dj = Dis[jb * 64 + lane];
      float T = 0.f;
#pragma unroll
      for (int k = 0; k < 8; ++k)
        T += __shfl(M, a * 8 + k, 64) * __shfl(dj, k * 8 + b, 64);
      float o = 0.f;
#pragma unroll
      for (int k = 0; k < 8; ++k)
        o += __shfl(di, a * 8 + k, 64) * __shfl(T, k * 8 + b, 64);
      Bc[s + 1][lane] = o;
      if (lane == 0) jl[s + 1] = jb;
    }
  }
  __syncthreads();  // drains zero-stores; scatter lands after (same-address safe)

  // ---- scatter nonzero blocks from LDS over the zeros ----
  int tot = c + 1;
  for (int s = wid; s < tot; s += 4)
    out[(size_t)(i * 8 + a) * ND + jl[s] * 8 + b] = Bc[s][lane];
}

extern "C" void kernel_launch(void* const* d_in, const int* in_sizes, int n_in,
                              void* d_out, int out_size, void* d_ws, size_t ws_size,
                              hipStream_t stream) {
  const float* R = (const float*)d_in[0];
  const int* eidx = (const int*)d_in[1];
  // d_in[2] = num_edges (device scalar; statically 1024)
  const float* L1 = (const float*)d_in[3];
  float* out = (float*)d_out;
  int P = in_sizes[0] / 64;  // 32768

  int* cnt = (int*)d_ws;                                // 4 KiB
  int* rowlist = cnt + N;                               // 384 KiB
  float* diag = (float*)(rowlist + (size_t)N * MAXB);   // 256 KiB
  float* Dis = diag + (size_t)N * 64;                   // 256 KiB

  hipMemsetAsync(cnt, 0, N * sizeof(int), stream);
  k_count<<<P / 256, 256, 0, stream>>>(eidx, P, cnt, rowlist);
  k_diagdis<<<N, 256, 0, stream>>>(R, cnt, rowlist, diag, Dis);
  k_out<<<N, 256, 0, stream>>>(R, eidx, L1, cnt, rowlist, diag, Dis, P, out);
}

// Round 7
// 95.390 us; speedup vs baseline: 1.1782x; 1.1782x over previous
//
#include <hip/hip_runtime.h>
#include <cstddef>
#include <cstdint>

// EdgeSheafLaplacian: n=1024 nodes, stalk d=8, P=32768 directed edges.
// Output Delta (8192 x 8192) f32: only 1024 diag + P edge blocks nonzero.
//
// R7: minimal-dispatch fill+scatter (the structure that measured best).
//   memset cnt (4 KiB)
//   K1 k_countfill: blocks 0..127 bucket edges by source node (32K int
//                   atomics), then ALL 4096 blocks grid-stride zero-fill the
//                   268 MB output with dwordx4 stores (pure fill rate).
//   K2 k_diagdis:   1024 blocks, 4 waves/node: FtF partials over bucket list,
//                   LDS-reduce, Newton-Schulz D^{-1/2}.
//                   (valid: D = sum-of-Wisharts + eps I => lambda_min >> eps,
//                    reference's clip(w,EPS) inactive; eigh not needed)
//   K3 k_scatter:   one wave per nonzero block (P edges + N diags): compute
//                   Dis_i * M * Dis_j via wave shuffles, write 8x32B rows.
// Reverse edge is structural: directed = [lo,hi ; hi,lo] concat -> rev = p +- P/2
// (verified in-kernel; mismatch or sign(L1)==0 -> block is exactly zero).

namespace {
constexpr int N = 1024;
constexpr int ND = 8192;
constexpr int MAXB = 96;       // bucket capacity (deg mean 32, sigma ~5.7)
constexpr int FILLB = 4096;    // fill grid
}

__global__ __launch_bounds__(256) void k_countfill(const int* __restrict__ eidx,
                                                   int P, int* __restrict__ cnt,
                                                   int* __restrict__ rowlist,
                                                   float* __restrict__ out) {
  const int bid = blockIdx.x;
  const int tid = threadIdx.x;
  // ---- bucket edges (blocks 0..P/256-1) ----
  if (bid < (P >> 8)) {
    int p = (bid << 8) + tid;
    int i = ((const int2*)eidx)[p].x;
    int slot = atomicAdd(&cnt[i], 1);
    if (slot < MAXB) rowlist[i * MAXB + slot] = p;
  }
  // ---- grid-stride zero-fill: 16.78M float4 over 4096*256 threads ----
  float4 z = {0.f, 0.f, 0.f, 0.f};
  float4* ob = (float4*)out;
  size_t idx = (size_t)bid * 256 + tid;
  const size_t stride = (size_t)FILLB * 256;
  const size_t total = (size_t)ND * ND / 4;
#pragma unroll 4
  for (; idx < total; idx += stride) ob[idx] = z;
}

__global__ __launch_bounds__(256) void k_diagdis(const float* __restrict__ R,
                                                 const int* __restrict__ cnt,
                                                 const int* __restrict__ rowlist,
                                                 float* __restrict__ diag,
                                                 float* __restrict__ Dis) {
  const int v = blockIdx.x;
  const int tid = threadIdx.x;
  const int wid = tid >> 6, lane = tid & 63;
  const int a = lane >> 3, b = lane & 7;
  int c = cnt[v];
  if (c > MAXB) c = MAXB;
  float acc = 0.f;
  for (int s = wid; s < c; s += 4) {
    int p = rowlist[v * MAXB + s];
    float r = R[(size_t)p * 64 + lane];
#pragma unroll
    for (int k = 0; k < 8; ++k)
      acc += __shfl(r, k * 8 + a, 64) * __shfl(r, k * 8 + b, 64);
  }
  __shared__ float part[4][64];
  part[wid][lane] = acc;
  __syncthreads();
  if (wid != 0) return;
  float tot = (part[0][lane] + part[1][lane]) + (part[2][lane] + part[3][lane]);
  diag[v * 64 + lane] = tot;  // bitwise symmetric (commutative products, fixed order)
  float A = tot + (a == b ? 1e-4f : 0.f);
  float sq = A * A;
#pragma unroll
  for (int off = 32; off; off >>= 1) sq += __shfl_xor(sq, off, 64);
  float fro = sqrtf(sq);
  // Newton-Schulz: Y0 = A/fro (spectrum in (0,1]), Z0 = I; Z -> (A/fro)^{-1/2}
  float Y = A * (1.f / fro);
  float Z = (a == b) ? 1.f : 0.f;
  for (int it = 0; it < 14; ++it) {
    float T = 0.f;
#pragma unroll
    for (int k = 0; k < 8; ++k)
      T += __shfl(Z, a * 8 + k, 64) * __shfl(Y, k * 8 + b, 64);
    float G = ((a == b) ? 1.5f : 0.f) - 0.5f * T;  // (3I - ZY)/2
    float Yn = 0.f, Zn = 0.f;
#pragma unroll
    for (int k = 0; k < 8; ++k) {
      Yn += __shfl(Y, a * 8 + k, 64) * __shfl(G, k * 8 + b, 64);
      Zn += __shfl(G, a * 8 + k, 64) * __shfl(Z, k * 8 + b, 64);
    }
    Y = Yn;
    Z = Zn;
  }
  Dis[v * 64 + lane] = Z * (1.f / sqrtf(fro));
}

__global__ __launch_bounds__(256) void k_scatter(const float* __restrict__ R,
                                                 const int* __restrict__ eidx,
                                                 const float* __restrict__ L1,
                                                 const float* __restrict__ diag,
                                                 const float* __restrict__ Dis, int P,
                                                 float* __restrict__ out) {
  int gid = blockIdx.x * blockDim.x + threadIdx.x;
  int u = gid >> 6;
  if (u >= P + N) return;
  const int lane = gid & 63;
  const int a = lane >> 3, b = lane & 7;
  int i, j;
  float M;
  if (u < P) {
    int p = u;
    int2 e = ((const int2*)eidx)[p];
    i = e.x;
    j = e.y;
    int halfP = P >> 1;
    int rev = (p < halfP) ? p + halfP : p - halfP;  // structural reverse edge
    int2 er = ((const int2*)eidx)[rev];
    bool ok = (er.x == j) && (er.y == i);
    float l1v = L1[i * N + j];
    float sgn = (l1v > 0.f ? 1.f : 0.f) - (l1v < 0.f ? 1.f : 0.f);
    if (!ok || sgn == 0.f) return;  // block exactly zero: keep filled zeros
    float rp = R[(size_t)p * 64 + lane];
    float rr = R[(size_t)rev * 64 + lane];
    float m = 0.f;
#pragma unroll
    for (int k = 0; k < 8; ++k)
      m += __shfl(rr, k * 8 + a, 64) * __shfl(rp, k * 8 + b, 64);
    M = -sgn * m;
  } else {
    int v = u - P;
    i = v;
    j = v;
    M = diag[v * 64 + lane];
  }
  float di = Dis[i * 64 + lane];
  float dj = Dis[j * 64 + lane];
  float T = 0.f;
#pragma unroll
  for (int k = 0; k < 8; ++k)
    T += __shfl(M, a * 8 + k, 64) * __shfl(dj, k * 8 + b, 64);
  float o = 0.f;
#pragma unroll
  for (int k = 0; k < 8; ++k)
    o += __shfl(di, a * 8 + k, 64) * __shfl(T, k * 8 + b, 64);
  out[(size_t)(i * 8 + a) * ND + j * 8 + b] = o;
}

extern "C" void kernel_launch(void* const* d_in, const int* in_sizes, int n_in,
                              void* d_out, int out_size, void* d_ws, size_t ws_size,
                              hipStream_t stream) {
  const float* R = (const float*)d_in[0];
  const int* eidx = (const int*)d_in[1];
  // d_in[2] = num_edges (device scalar; statically 1024)
  const float* L1 = (const float*)d_in[3];
  float* out = (float*)d_out;
  int P = in_sizes[0] / 64;  // 32768

  int* cnt = (int*)d_ws;                                // 4 KiB
  int* rowlist = cnt + N;                               // 384 KiB
  float* diag = (float*)(rowlist + (size_t)N * MAXB);   // 256 KiB
  float* Dis = diag + (size_t)N * 64;                   // 256 KiB

  hipMemsetAsync(cnt, 0, N * sizeof(int), stream);
  k_countfill<<<FILLB, 256, 0, stream>>>(eidx, P, cnt, rowlist, out);
  k_diagdis<<<N, 256, 0, stream>>>(R, cnt, rowlist, diag, Dis);
  k_scatter<<<(P + N + 3) / 4, 256, 0, stream>>>(R, eidx, L1, diag, Dis, P, out);
}

// Round 8
// 92.936 us; speedup vs baseline: 1.2093x; 1.0264x over previous
//
#include <hip/hip_runtime.h>
#include <cstddef>
#include <cstdint>

// EdgeSheafLaplacian: n=1024 nodes, stalk d=8, P=32768 directed edges.
// Output Delta (8192 x 8192) f32: only 1024 diag + P edge blocks nonzero.
//
// R8: vendor fill for the 268MB zero write (measured 6.6-6.8 TB/s; all custom
// writers measured ~3.4 TB/s), plus the measured-fast small kernels:
//   memset cnt (4 KiB)
//   K1 k_count:   bucket edges by source node (32K int atomics)
//   K2 k_diagdis: 1024 blocks, 4 waves/node: FtF partials over bucket list,
//                 LDS-reduce, Newton-Schulz D^{-1/2}.
//                 (valid: D = sum-of-Wisharts + eps I => lambda_min >> eps,
//                  reference's clip(w,EPS) is inactive; eigh not needed)
//   memset out (vendor fillBufferAligned, 268 MB)
//   K3 k_scatter: one wave per nonzero block (P edges + N diags): compute
//                 Dis_i * M * Dis_j via wave shuffles, write 8x32B rows.
// Reverse edge is structural: directed = [lo,hi ; hi,lo] concat -> rev = p +- P/2
// (verified in-kernel; mismatch or sign(L1)==0 -> block is exactly zero).

namespace {
constexpr int N = 1024;
constexpr int ND = 8192;
constexpr int MAXB = 96;  // bucket capacity (deg mean 32, sigma ~5.7)
}

__global__ __launch_bounds__(256) void k_count(const int* __restrict__ eidx, int P,
                                               int* __restrict__ cnt,
                                               int* __restrict__ rowlist) {
  int p = blockIdx.x * blockDim.x + threadIdx.x;
  if (p >= P) return;
  int i = ((const int2*)eidx)[p].x;
  int slot = atomicAdd(&cnt[i], 1);
  if (slot < MAXB) rowlist[i * MAXB + slot] = p;
}

__global__ __launch_bounds__(256) void k_diagdis(const float* __restrict__ R,
                                                 const int* __restrict__ cnt,
                                                 const int* __restrict__ rowlist,
                                                 float* __restrict__ diag,
                                                 float* __restrict__ Dis) {
  const int v = blockIdx.x;
  const int tid = threadIdx.x;
  const int wid = tid >> 6, lane = tid & 63;
  const int a = lane >> 3, b = lane & 7;
  int c = cnt[v];
  if (c > MAXB) c = MAXB;
  float acc = 0.f;
  for (int s = wid; s < c; s += 4) {
    int p = rowlist[v * MAXB + s];
    float r = R[(size_t)p * 64 + lane];
#pragma unroll
    for (int k = 0; k < 8; ++k)
      acc += __shfl(r, k * 8 + a, 64) * __shfl(r, k * 8 + b, 64);
  }
  __shared__ float part[4][64];
  part[wid][lane] = acc;
  __syncthreads();
  if (wid != 0) return;
  float tot = (part[0][lane] + part[1][lane]) + (part[2][lane] + part[3][lane]);
  diag[v * 64 + lane] = tot;  // bitwise symmetric (commutative products, fixed order)
  float A = tot + (a == b ? 1e-4f : 0.f);
  float sq = A * A;
#pragma unroll
  for (int off = 32; off; off >>= 1) sq += __shfl_xor(sq, off, 64);
  float fro = sqrtf(sq);
  // Newton-Schulz: Y0 = A/fro (spectrum in (0,1]), Z0 = I; Z -> (A/fro)^{-1/2}
  float Y = A * (1.f / fro);
  float Z = (a == b) ? 1.f : 0.f;
  for (int it = 0; it < 14; ++it) {
    float T = 0.f;
#pragma unroll
    for (int k = 0; k < 8; ++k)
      T += __shfl(Z, a * 8 + k, 64) * __shfl(Y, k * 8 + b, 64);
    float G = ((a == b) ? 1.5f : 0.f) - 0.5f * T;  // (3I - ZY)/2
    float Yn = 0.f, Zn = 0.f;
#pragma unroll
    for (int k = 0; k < 8; ++k) {
      Yn += __shfl(Y, a * 8 + k, 64) * __shfl(G, k * 8 + b, 64);
      Zn += __shfl(G, a * 8 + k, 64) * __shfl(Z, k * 8 + b, 64);
    }
    Y = Yn;
    Z = Zn;
  }
  Dis[v * 64 + lane] = Z * (1.f / sqrtf(fro));
}

__global__ __launch_bounds__(256) void k_scatter(const float* __restrict__ R,
                                                 const int* __restrict__ eidx,
                                                 const float* __restrict__ L1,
                                                 const float* __restrict__ diag,
                                                 const float* __restrict__ Dis, int P,
                                                 float* __restrict__ out) {
  int gid = blockIdx.x * blockDim.x + threadIdx.x;
  int u = gid >> 6;
  if (u >= P + N) return;
  const int lane = gid & 63;
  const int a = lane >> 3, b = lane & 7;
  int i, j;
  float M;
  if (u < P) {
    int p = u;
    int2 e = ((const int2*)eidx)[p];
    i = e.x;
    j = e.y;
    int halfP = P >> 1;
    int rev = (p < halfP) ? p + halfP : p - halfP;  // structural reverse edge
    int2 er = ((const int2*)eidx)[rev];
    bool ok = (er.x == j) && (er.y == i);
    float l1v = L1[i * N + j];
    float sgn = (l1v > 0.f ? 1.f : 0.f) - (l1v < 0.f ? 1.f : 0.f);
    if (!ok || sgn == 0.f) return;  // block exactly zero: keep filled zeros
    float rp = R[(size_t)p * 64 + lane];
    float rr = R[(size_t)rev * 64 + lane];
    float m = 0.f;
#pragma unroll
    for (int k = 0; k < 8; ++k)
      m += __shfl(rr, k * 8 + a, 64) * __shfl(rp, k * 8 + b, 64);
    M = -sgn * m;
  } else {
    int v = u - P;
    i = v;
    j = v;
    M = diag[v * 64 + lane];
  }
  float di = Dis[i * 64 + lane];
  float dj = Dis[j * 64 + lane];
  float T = 0.f;
#pragma unroll
  for (int k = 0; k < 8; ++k)
    T += __shfl(M, a * 8 + k, 64) * __shfl(dj, k * 8 + b, 64);
  float o = 0.f;
#pragma unroll
  for (int k = 0; k < 8; ++k)
    o += __shfl(di, a * 8 + k, 64) * __shfl(T, k * 8 + b, 64);
  out[(size_t)(i * 8 + a) * ND + j * 8 + b] = o;
}

extern "C" void kernel_launch(void* const* d_in, const int* in_sizes, int n_in,
                              void* d_out, int out_size, void* d_ws, size_t ws_size,
                              hipStream_t stream) {
  const float* R = (const float*)d_in[0];
  const int* eidx = (const int*)d_in[1];
  // d_in[2] = num_edges (device scalar; statically 1024)
  const float* L1 = (const float*)d_in[3];
  float* out = (float*)d_out;
  int P = in_sizes[0] / 64;  // 32768

  int* cnt = (int*)d_ws;                                // 4 KiB
  int* rowlist = cnt + N;                               // 384 KiB
  float* diag = (float*)(rowlist + (size_t)N * MAXB);   // 256 KiB
  float* Dis = diag + (size_t)N * 64;                   // 256 KiB

  hipMemsetAsync(cnt, 0, N * sizeof(int), stream);
  k_count<<<P / 256, 256, 0, stream>>>(eidx, P, cnt, rowlist);
  k_diagdis<<<N, 256, 0, stream>>>(R, cnt, rowlist, diag, Dis);
  hipMemsetAsync(out, 0, (size_t)out_size * sizeof(float), stream);
  k_scatter<<<(P + N + 3) / 4, 256, 0, stream>>>(R, eidx, L1, diag, Dis, P, out);
}

// Round 9
// 88.276 us; speedup vs baseline: 1.2731x; 1.0528x over previous
//
#include <hip/hip_runtime.h>
#include <cstddef>
#include <cstdint>

// EdgeSheafLaplacian: n=1024 nodes, stalk d=8, P=32768 directed edges.
// Output Delta (8192 x 8192) f32: only 1024 diag + P edge blocks nonzero.
//
// R9: 4 dispatches, single output write.
//   memset:  cnt (4 KiB) + diag (256 KiB) zero, contiguous.
//   K_A:     per-edge wave: FtF = R^T R via shuffles -> atomicAdd diag[i];
//            lane0 bucket-appends edge into rowlist[i] (fused k_build+k_count).
//   K_B:     per-node wave: Newton-Schulz D^{-1/2} from diag -> Dis.
//            (valid: D = sum-of-Wisharts + eps I => lambda_min >> eps, so the
//             reference's clip(w,EPS) is inactive; eigh not needed)
//   K_C:     per block-row i: stage slot metadata with c PARALLEL threads
//            (rowlist -> eidx -> rev-check -> L1 sign), 4 waves compute
//            normalized blocks into LDS, then gather-stream the full
//            8 x 8192 row once (float4, LDS map select). No scatter pass.
// Reverse edge is structural: directed = [lo,hi ; hi,lo] concat -> rev = p +- P/2
// (verified in-kernel; mismatch or sign(L1)==0 -> block is exactly zero).

namespace {
constexpr int N = 1024;
constexpr int ND = 8192;
constexpr int MAXB = 96;  // bucket capacity (deg mean 32, sigma ~5.7)
}

__global__ __launch_bounds__(256) void k_build(const float* __restrict__ R,
                                               const int* __restrict__ eidx, int P,
                                               int* __restrict__ cnt,
                                               int* __restrict__ rowlist,
                                               float* __restrict__ diag) {
  int gid = blockIdx.x * blockDim.x + threadIdx.x;
  int u = gid >> 6;
  if (u >= P) return;
  const int lane = gid & 63;
  const int a = lane >> 3, b = lane & 7;
  int2 e = ((const int2*)eidx)[u];
  float r = R[(size_t)u * 64 + lane];
  float acc = 0.f;
#pragma unroll
  for (int k = 0; k < 8; ++k)
    acc += __shfl(r, k * 8 + a, 64) * __shfl(r, k * 8 + b, 64);
  atomicAdd(&diag[e.x * 64 + lane], acc);
  if (lane == 0) {
    int slot = atomicAdd(&cnt[e.x], 1);
    if (slot < MAXB) rowlist[e.x * MAXB + slot] = u;
  }
}

__global__ __launch_bounds__(256) void k_invsqrt(const float* __restrict__ diag,
                                                 float* __restrict__ Dis) {
  const int tid = threadIdx.x;
  const int wid = tid >> 6, lane = tid & 63;
  const int a = lane >> 3, b = lane & 7;
  const int v = (blockIdx.x << 2) + wid;
  float dv = diag[v * 64 + lane];  // symmetric by construction
  float A = dv + (a == b ? 1e-4f : 0.f);
  float sq = A * A;
#pragma unroll
  for (int off = 32; off; off >>= 1) sq += __shfl_xor(sq, off, 64);
  float fro = sqrtf(sq);
  // Newton-Schulz: Y0 = A/fro (spectrum in (0,1]), Z0 = I; Z -> (A/fro)^{-1/2}
  float Y = A * (1.f / fro);
  float Z = (a == b) ? 1.f : 0.f;
  for (int it = 0; it < 14; ++it) {
    float T = 0.f;
#pragma unroll
    for (int k = 0; k < 8; ++k)
      T += __shfl(Z, a * 8 + k, 64) * __shfl(Y, k * 8 + b, 64);
    float G = ((a == b) ? 1.5f : 0.f) - 0.5f * T;  // (3I - ZY)/2
    float Yn = 0.f, Zn = 0.f;
#pragma unroll
    for (int k = 0; k < 8; ++k) {
      Yn += __shfl(Y, a * 8 + k, 64) * __shfl(G, k * 8 + b, 64);
      Zn += __shfl(G, a * 8 + k, 64) * __shfl(Z, k * 8 + b, 64);
    }
    Y = Yn;
    Z = Zn;
  }
  Dis[v * 64 + lane] = Z * (1.f / sqrtf(fro));
}

__global__ __launch_bounds__(256) void k_out(
    const float* __restrict__ R, const int* __restrict__ eidx,
    const float* __restrict__ L1, const int* __restrict__ cnt,
    const int* __restrict__ rowlist, const float* __restrict__ diag,
    const float* __restrict__ Dis, int P, float* __restrict__ out) {
  const int i = blockIdx.x;
  const int tid = threadIdx.x;
  const int wid = tid >> 6, lane = tid & 63;
  const int a = lane >> 3, b = lane & 7;
  __shared__ float Bc[MAXB + 1][64];  // slot 0 = diag block
  __shared__ short map[N];            // column-block -> slot, -1 = zero
  __shared__ int sp[MAXB], srev[MAXB], sj[MAXB];
  __shared__ float ssgn[MAXB];        // 0 => block exactly zero

  for (int t = tid; t < N; t += 256) map[t] = -1;
  int c = cnt[i];
  if (c > MAXB) c = MAXB;
  const int halfP = P >> 1;

  // ---- stage 1: parallel metadata fetch (c threads, 2 latency rounds) ----
  if (tid < c) {
    int p = rowlist[i * MAXB + tid];
    int2 e = ((const int2*)eidx)[p];
    int rev = (p < halfP) ? p + halfP : p - halfP;  // structural reverse edge
    int2 er = ((const int2*)eidx)[rev];
    bool ok = (er.x == e.y) && (er.y == i);
    float l1v = L1[i * N + e.y];
    float sgn = (l1v > 0.f ? 1.f : 0.f) - (l1v < 0.f ? 1.f : 0.f);
    sp[tid] = p;
    srev[tid] = rev;
    sj[tid] = e.y;
    ssgn[tid] = ok ? -sgn : 0.f;
    map[e.y] = (short)(tid + 1);
  }
  if (tid == 0) map[i] = 0;
  __syncthreads();

  // ---- stage 2: compute normalized blocks into LDS (4 waves, strided) ----
  const float di = Dis[i * 64 + lane];
  if (wid == 0) {
    float M = diag[i * 64 + lane];
    float T = 0.f;
#pragma unroll
    for (int k = 0; k < 8; ++k)
      T += __shfl(M, a * 8 + k, 64) * __shfl(di, k * 8 + b, 64);
    float o = 0.f;
#pragma unroll
    for (int k = 0; k < 8; ++k)
      o += __shfl(di, a * 8 + k, 64) * __shfl(T, k * 8 + b, 64);
    Bc[0][lane] = o;
  }
  for (int s = wid; s < c; s += 4) {
    float sgn = ssgn[s];
    float o = 0.f;
    if (sgn != 0.f) {
      float rp = R[(size_t)sp[s] * 64 + lane];
      float rr = R[(size_t)srev[s] * 64 + lane];
      float dj = Dis[sj[s] * 64 + lane];
      float m = 0.f;
#pragma unroll
      for (int k = 0; k < 8; ++k)
        m += __shfl(rr, k * 8 + a, 64) * __shfl(rp, k * 8 + b, 64);
      m *= sgn;  // = -sign(L1) * m
      float T = 0.f;
#pragma unroll
      for (int k = 0; k < 8; ++k)
        T += __shfl(m, a * 8 + k, 64) * __shfl(dj, k * 8 + b, 64);
#pragma unroll
      for (int k = 0; k < 8; ++k)
        o += __shfl(di, a * 8 + k, 64) * __shfl(T, k * 8 + b, 64);
    }
    Bc[s + 1][lane] = o;
  }
  __syncthreads();

  // ---- stage 3: single-pass gather-stream of rows [8i, 8i+8) ----
#pragma unroll
  for (int rrow = 0; rrow < 8; ++rrow) {
    float4* orow = (float4*)(out + (size_t)(i * 8 + rrow) * ND);
#pragma unroll
    for (int kk = 0; kk < 8; ++kk) {
      int c4 = kk * 256 + tid;  // 0..2047
      int jb = c4 >> 1, half = c4 & 1;
      int slot = map[jb];
      float4 v = {0.f, 0.f, 0.f, 0.f};
      if (slot >= 0) v = *(const float4*)(&Bc[slot][rrow * 8 + half * 4]);
      orow[c4] = v;
    }
  }
}

extern "C" void kernel_launch(void* const* d_in, const int* in_sizes, int n_in,
                              void* d_out, int out_size, void* d_ws, size_t ws_size,
                              hipStream_t stream) {
  const float* R = (const float*)d_in[0];
  const int* eidx = (const int*)d_in[1];
  // d_in[2] = num_edges (device scalar; statically 1024)
  const float* L1 = (const float*)d_in[3];
  float* out = (float*)d_out;
  int P = in_sizes[0] / 64;  // 32768

  int* cnt = (int*)d_ws;                            // 4 KiB
  float* diag = (float*)(cnt + N);                  // 256 KiB (contiguous w/ cnt)
  int* rowlist = (int*)(diag + (size_t)N * 64);     // 384 KiB
  float* Dis = (float*)(rowlist + (size_t)N * MAXB);// 256 KiB

  hipMemsetAsync(cnt, 0, N * sizeof(int) + (size_t)N * 64 * sizeof(float), stream);
  k_build<<<(P * 64) / 256, 256, 0, stream>>>(R, eidx, P, cnt, rowlist, diag);
  k_invsqrt<<<N / 4, 256, 0, stream>>>(diag, Dis);
  k_out<<<N, 256, 0, stream>>>(R, eidx, L1, cnt, rowlist, diag, Dis, P, out);
}